// Round 1
// baseline (591.825 us; speedup 1.0000x reference)
//
#include <hip/hip_runtime.h>
#include <hip/hip_bf16.h>
#include <math.h>

typedef __attribute__((ext_vector_type(4))) float fx4;
typedef __attribute__((ext_vector_type(8))) short bx8;   // 8 bf16 (one MFMA A/B fragment)
typedef __attribute__((ext_vector_type(4))) short bx4;   // 4 bf16

#define DEV static __device__ __forceinline__

DEV unsigned short f2bf(float f){
  union { float f; unsigned u; } a; a.f = f;
  unsigned r = a.u + 0x7FFFu + ((a.u >> 16) & 1u);   // RNE
  return (unsigned short)(r >> 16);
}
DEV float bf2f(unsigned short h){
  union { float f; unsigned u; } a; a.u = ((unsigned)h) << 16;
  return a.f;
}
DEV float fast_tanh(float x){
  // tanh(x) = 1 - 2/(exp(2x)+1); exact at +/-inf saturation, ~1e-6 rel err
  return 1.0f - 2.0f / (__expf(2.0f * x) + 1.0f);
}

// ---------------- K0: weights fp32 [K][N] -> bf16 transposed [N][K] ----------------
// Wn 256x128 -> WnT 128x256 ; Wd 64x128 -> WdT 128x64 ; We 128x128 -> WeT 128x128 ;
// Wc 256x256 -> WcT 256x256.  Total 122880 elements = 480 blocks * 256.
__global__ void prep_kernel(const float* __restrict__ Wn, const float* __restrict__ Wd,
                            const float* __restrict__ We, const float* __restrict__ Wc,
                            unsigned short* __restrict__ WnT, unsigned short* __restrict__ WdT,
                            unsigned short* __restrict__ WeT, unsigned short* __restrict__ WcT)
{
  int t = blockIdx.x * 256 + threadIdx.x;
  if (t < 32768)      { int k = t >> 7, n = t & 127;                 WnT[n*256 + k] = f2bf(Wn[t]); }
  else if (t < 40960) { int i = t - 32768; int k = i >> 7, n = i & 127; WdT[n*64  + k] = f2bf(Wd[i]); }
  else if (t < 57344) { int i = t - 40960; int k = i >> 7, n = i & 127; WeT[n*128 + k] = f2bf(We[i]); }
  else if (t < 122880){ int i = t - 57344; int k = i >> 8, n = i & 255; WcT[n*256 + k] = f2bf(Wc[i]); }
}

// ---------------- K1: node_proj = bf16(node_h @ W_node + b_node)  [20000][128] ----------------
// 1 wave per 16 rows. A staged in LDS bf16, B fragments straight from L2-resident WnT.
__global__ __launch_bounds__(64)
void node_proj_kernel(const float* __restrict__ node_h, const unsigned short* __restrict__ WnT,
                      const float* __restrict__ b_node, unsigned short* __restrict__ npj)
{
  __shared__ unsigned short sN[16 * 264];             // pitch 264 bf16 (16B pad -> 4-bank row skew)
  const int lane = threadIdx.x;
  const int lr = lane & 15, lq = lane >> 4;
  const long r0 = (long)blockIdx.x * 16;

  const fx4* g = (const fx4*)(node_h + r0 * 256);
#pragma unroll
  for (int i = 0; i < 16; ++i){
    int idx = lane + 64 * i;                          // 0..1023 f4 chunks
    int r = idx >> 6, c4 = idx & 63;
    fx4 v = g[idx];
    bx4 b;
    b[0]=(short)f2bf(v[0]); b[1]=(short)f2bf(v[1]); b[2]=(short)f2bf(v[2]); b[3]=(short)f2bf(v[3]);
    *(bx4*)&sN[r*264 + c4*4] = b;
  }
  __syncthreads();

  fx4 acc[8];
#pragma unroll
  for (int n = 0; n < 8; ++n) acc[n] = (fx4){0.f,0.f,0.f,0.f};
#pragma unroll
  for (int ks = 0; ks < 8; ++ks){                     // K = 256
    bx8 a = *(const bx8*)&sN[lr*264 + ks*32 + lq*8];
#pragma unroll
    for (int n = 0; n < 8; ++n){                      // N = 128
      bx8 b = *(const bx8*)&WnT[(n*16 + lr)*256 + ks*32 + lq*8];
      acc[n] = __builtin_amdgcn_mfma_f32_16x16x32_bf16(a, b, acc[n], 0, 0, 0);
    }
  }
#pragma unroll
  for (int n = 0; n < 8; ++n){
    float bias = b_node[n*16 + lr];
#pragma unroll
    for (int j = 0; j < 4; ++j)                       // D: col=lr, row=lq*4+j
      npj[(r0 + lq*4 + j)*128 + n*16 + lr] = f2bf(acc[n][j] + bias);
  }
}

// ---------------- K2: fused per-edge pipeline, 64 edges/block, 4 waves ----------------
// LDS plan (aliased, 51.7KB):
//   region A [0,17408):        sDP (dist_proj bf16 [64][136]); sD (dist bf16 [64][72]) aliases [0,9216)
//   region B [17408,51200):    sX  (concat bf16 [64][264]);    sE (edge bf16 [64][136]) aliases first 34816B... (dead before sX writes)
//   ids at [51200,51712)
__global__ __launch_bounds__(256, 2)
void edge_kernel(const float* __restrict__ edge_h, const float* __restrict__ dist,
                 const int* __restrict__ src, const int* __restrict__ dst,
                 const unsigned short* __restrict__ npj,
                 const unsigned short* __restrict__ WdT, const float* __restrict__ b_dist,
                 const unsigned short* __restrict__ WeT, const float* __restrict__ b_edge,
                 const unsigned short* __restrict__ WcT,
                 float* __restrict__ hacc)
{
  __shared__ __attribute__((aligned(16))) char lds[51712];
  unsigned short* const sDP = (unsigned short*)lds;            // [64][136]
  unsigned short* const sD  = (unsigned short*)lds;            // [64][72]  (alias, dead before sDP written)
  unsigned short* const sX  = (unsigned short*)(lds + 17408);  // [64][264]
  unsigned short* const sE  = (unsigned short*)(lds + 17408);  // [64][136] (alias, dead before sX written)
  int* const sSrc = (int*)(lds + 51200);
  int* const sDst = (int*)(lds + 51456);

  const int tid  = threadIdx.x;
  const int wave = tid >> 6;
  const int lane = tid & 63;
  const int lr   = lane & 15;
  const int lq   = lane >> 4;
  const long e0  = (long)blockIdx.x * 64;

  if (tid < 64){ sSrc[tid] = src[e0 + tid]; sDst[tid] = dst[e0 + tid]; }

  // ---- stage dist [64][64] and edge_h [64][128] as bf16 ----
  {
    const fx4* g = (const fx4*)(dist + e0 * 64);
#pragma unroll
    for (int i = 0; i < 4; ++i){
      int idx = tid + 256*i;                 // 1024 f4 chunks
      int r = idx >> 4, c4 = idx & 15;
      fx4 v = g[idx];
      bx4 b;
      b[0]=(short)f2bf(v[0]); b[1]=(short)f2bf(v[1]); b[2]=(short)f2bf(v[2]); b[3]=(short)f2bf(v[3]);
      *(bx4*)&sD[r*72 + c4*4] = b;
    }
    const fx4* ge = (const fx4*)(edge_h + e0 * 128);
#pragma unroll
    for (int i = 0; i < 8; ++i){
      int idx = tid + 256*i;                 // 2048 f4 chunks
      int r = idx >> 5, c4 = idx & 31;
      fx4 v = ge[idx];
      bx4 b;
      b[0]=(short)f2bf(v[0]); b[1]=(short)f2bf(v[1]); b[2]=(short)f2bf(v[2]); b[3]=(short)f2bf(v[3]);
      *(bx4*)&sE[r*136 + c4*4] = b;
    }
  }
  __syncthreads();   // bar1: staging + ids complete

  // ---- dist GEMM: M=64 (all rows), wave covers cols [32*wave, 32*wave+32), K=64 ----
  {
    fx4 acc[4][2];
#pragma unroll
    for (int rt=0;rt<4;++rt)
#pragma unroll
      for (int n=0;n<2;++n) acc[rt][n] = (fx4){0.f,0.f,0.f,0.f};
#pragma unroll
    for (int ks = 0; ks < 2; ++ks){
      bx8 a[4], b[2];
#pragma unroll
      for (int rt = 0; rt < 4; ++rt)
        a[rt] = *(const bx8*)&sD[(rt*16 + lr)*72 + ks*32 + lq*8];
#pragma unroll
      for (int n = 0; n < 2; ++n)
        b[n] = *(const bx8*)&WdT[((2*wave + n)*16 + lr)*64 + ks*32 + lq*8];
#pragma unroll
      for (int rt = 0; rt < 4; ++rt)
#pragma unroll
        for (int n = 0; n < 2; ++n)
          acc[rt][n] = __builtin_amdgcn_mfma_f32_16x16x32_bf16(a[rt], b[n], acc[rt][n], 0, 0, 0);
    }
    __syncthreads();  // bar2: all waves done reading sD before sDP (alias) is written
#pragma unroll
    for (int rt=0;rt<4;++rt)
#pragma unroll
      for (int n=0;n<2;++n)
#pragma unroll
        for (int j=0;j<4;++j)
          sDP[(rt*16 + lq*4 + j)*136 + (2*wave + n)*16 + lr] = f2bf(acc[rt][n][j]);
  }

  // ---- edge GEMM: M=64, wave cols [32*wave,+32), K=128 -> sX[:,128+...] ----
  {
    fx4 acc[4][2];
#pragma unroll
    for (int rt=0;rt<4;++rt)
#pragma unroll
      for (int n=0;n<2;++n) acc[rt][n] = (fx4){0.f,0.f,0.f,0.f};
#pragma unroll
    for (int ks = 0; ks < 4; ++ks){
      bx8 a[4], b[2];
#pragma unroll
      for (int rt = 0; rt < 4; ++rt)
        a[rt] = *(const bx8*)&sE[(rt*16 + lr)*136 + ks*32 + lq*8];
#pragma unroll
      for (int n = 0; n < 2; ++n)
        b[n] = *(const bx8*)&WeT[((2*wave + n)*16 + lr)*128 + ks*32 + lq*8];
#pragma unroll
      for (int rt = 0; rt < 4; ++rt)
#pragma unroll
        for (int n = 0; n < 2; ++n)
          acc[rt][n] = __builtin_amdgcn_mfma_f32_16x16x32_bf16(a[rt], b[n], acc[rt][n], 0, 0, 0);
    }
    __syncthreads();  // bar3: all waves done reading sE before sX (alias) is written
#pragma unroll
    for (int rt=0;rt<4;++rt)
#pragma unroll
      for (int n=0;n<2;++n){
        float be = b_edge[(2*wave + n)*16 + lr];
#pragma unroll
        for (int j=0;j<4;++j)
          sX[(rt*16 + lq*4 + j)*264 + 128 + (2*wave + n)*16 + lr] = f2bf(acc[rt][n][j] + be);
      }
  }

  // ---- m1 = node_proj[src] * (dist_proj + b_dist) -> sX[:, :128] (all threads cooperative) ----
#pragma unroll
  for (int i = 0; i < 8; ++i){
    int idx = tid + 256*i;                   // 2048 chunks of 4 cols
    int r = idx >> 5, ch = idx & 31;
    int s = sSrc[r];
    bx4 gnp = *(const bx4*)&npj[(long)s*128 + ch*4];
    bx4 dp  = *(const bx4*)&sDP[r*136 + ch*4];
    fx4 bd  = *(const fx4*)&b_dist[ch*4];
    bx4 o;
#pragma unroll
    for (int k = 0; k < 4; ++k)
      o[k] = (short)f2bf( bf2f((unsigned short)gnp[k]) * (bf2f((unsigned short)dp[k]) + bd[k]) );
    *(bx4*)&sX[r*264 + ch*4] = o;
  }
  __syncthreads();   // bar4: sX fully built

  // ---- comb GEMM: M=64, wave cols [64*wave,+64), K=256; tanh; atomic scatter ----
  {
    fx4 acc[4][4];
#pragma unroll
    for (int rt=0;rt<4;++rt)
#pragma unroll
      for (int n=0;n<4;++n) acc[rt][n] = (fx4){0.f,0.f,0.f,0.f};
#pragma unroll
    for (int ks = 0; ks < 8; ++ks){
      bx8 a[4], b[4];
#pragma unroll
      for (int rt = 0; rt < 4; ++rt)
        a[rt] = *(const bx8*)&sX[(rt*16 + lr)*264 + ks*32 + lq*8];
#pragma unroll
      for (int n = 0; n < 4; ++n)
        b[n] = *(const bx8*)&WcT[((4*wave + n)*16 + lr)*256 + ks*32 + lq*8];
#pragma unroll
      for (int rt = 0; rt < 4; ++rt)
#pragma unroll
        for (int n = 0; n < 4; ++n)
          acc[rt][n] = __builtin_amdgcn_mfma_f32_16x16x32_bf16(a[rt], b[n], acc[rt][n], 0, 0, 0);
    }
#pragma unroll
    for (int rt = 0; rt < 4; ++rt){
#pragma unroll
      for (int j = 0; j < 4; ++j){
        int d = sDst[rt*16 + lq*4 + j];
        long rowoff = (long)d * 256;
#pragma unroll
        for (int n = 0; n < 4; ++n){
          float t = fast_tanh(acc[rt][n][j]);
          atomicAdd(&hacc[rowoff + (4*wave + n)*16 + lr], t);
        }
      }
    }
  }
}

// ---------------- K3: in-place row L2-normalize of d_out [20000][256] ----------------
__global__ __launch_bounds__(256)
void norm_kernel(float* __restrict__ h)
{
  int row  = blockIdx.x * 4 + (threadIdx.x >> 6);
  int lane = threadIdx.x & 63;
  fx4 v = *(const fx4*)&h[(long)row*256 + lane*4];
  float s = v[0]*v[0] + v[1]*v[1] + v[2]*v[2] + v[3]*v[3];
#pragma unroll
  for (int off = 32; off > 0; off >>= 1) s += __shfl_xor(s, off);
  float inv = (s > 0.f) ? 1.0f / sqrtf(s) : 0.f;
  v[0]*=inv; v[1]*=inv; v[2]*=inv; v[3]*=inv;
  *(fx4*)&h[(long)row*256 + lane*4] = v;
}

extern "C" void kernel_launch(void* const* d_in, const int* in_sizes, int n_in,
                              void* d_out, int out_size, void* d_ws, size_t ws_size,
                              hipStream_t stream)
{
  const float* node_h = (const float*)d_in[0];
  const float* edge_h = (const float*)d_in[1];
  const float* dist   = (const float*)d_in[2];
  const int*   src    = (const int*)d_in[3];
  const int*   dst    = (const int*)d_in[4];
  const float* W_node = (const float*)d_in[5];
  const float* b_node = (const float*)d_in[6];
  const float* W_edge = (const float*)d_in[7];
  const float* b_edge = (const float*)d_in[8];
  const float* W_dist = (const float*)d_in[9];
  const float* b_dist = (const float*)d_in[10];
  const float* W_comb = (const float*)d_in[11];

  char* ws = (char*)d_ws;
  unsigned short* npj = (unsigned short*)ws;                    // 20000*128*2 = 5,120,000
  unsigned short* WnT = (unsigned short*)(ws + 5120000);        // +65536
  unsigned short* WdT = (unsigned short*)(ws + 5185536);        // +16384
  unsigned short* WeT = (unsigned short*)(ws + 5201920);        // +32768
  unsigned short* WcT = (unsigned short*)(ws + 5234688);        // +131072 -> 5,365,760 B total

  float* hacc = (float*)d_out;                                  // accumulate directly in output

  hipMemsetAsync(hacc, 0, (size_t)20000 * 256 * sizeof(float), stream);
  prep_kernel<<<480, 256, 0, stream>>>(W_node, W_dist, W_edge, W_comb, WnT, WdT, WeT, WcT);
  node_proj_kernel<<<1250, 64, 0, stream>>>(node_h, WnT, b_node, npj);
  edge_kernel<<<10000, 256, 0, stream>>>(edge_h, dist, src, dst, npj,
                                         WdT, b_dist, WeT, b_edge, WcT, hacc);
  norm_kernel<<<5000, 256, 0, stream>>>(hacc);
}